// Round 12
// baseline (196.396 us; speedup 1.0000x reference)
//
#include <hip/hip_runtime.h>

// GraphNet interaction network. Edge MLP via bf16 MFMA (fp32 accum).
// V21: SPLIT WORKING SET. r0-r11 synthesis: allocator splits the ~200-reg
// edge working set into ~108 VGPR + ~90 AGPR -> (a) combined footprint caps
// residency at 2 waves/SIMD (measured 1.4 avg), (b) MFMA-out->pack crossings
// pay accvgpr traffic (the 3-4x VALU inflation). Fix: W2 (64 regs, biggest
// block, pure MFMA-A operand) moves to 16KB LDS (16 ds_read_b128/tile,
// ~22us/CU pipe demand < wall); W1/W3/biases/state stay in regs (~144) with
// amdgpu_waves_per_eu(3) (170 budget) -> all-arch-VGPR, no AGPRs, residency
// cap 2->3 waves/SIMD. Edge body otherwise V13 (direct addressing, peeled
// s=0/s2=0 bias C-init, mask tile 11 only, cvt_pk, E1 prefetch).
// Also: fc23 FUSED into fc1 via per-batch arrival counter (8th fc1 block of
// a batch runs fc23 inline; prep zeroes counters) -> one fewer dispatch.
// obj RTO=16 376 blk, fc1 256 blk k-split, prep: r8-exact.
// Measurement note: ~80us of dur_us is harness 256MB workspace re-poison
// (2x40us fills at 6.6TB/s, r7 calibration) - uncontrollable floor.
#define BB   32
#define NN   188
#define PP   16
#define HID  128
#define HH2  64
#define DE   5
#define DO   6
#define NT   5
#define ROWS_O (BB*NN)
#define RTO  16
#define KO   (PP+DE)

typedef __attribute__((ext_vector_type(8))) short short8;     // 8 bf16 = 4 VGPRs
typedef __attribute__((ext_vector_type(4))) float float4_;
typedef __attribute__((ext_vector_type(4))) unsigned uint4_;

__device__ __forceinline__ short f2bf(float v) {              // RNE (prep only)
    union { float f; unsigned u; } a; a.f = v;
    unsigned r = a.u + 0x7fff + ((a.u >> 16) & 1);
    return (short)(r >> 16);
}
// relu both, then pack to 2xbf16 (RNE)
__device__ __forceinline__ unsigned relu_pk(float lo, float hi) {
    float l = lo > 0.f ? lo : 0.f;
    float h = hi > 0.f ? hi : 0.f;
    unsigned r;
    asm("v_cvt_pk_bf16_f32 %0, %1, %2" : "=v"(r) : "v"(l), "v"(h));
    return r;
}
__device__ __forceinline__ float4_ mfma16(short8 a, short8 b, float4_ c) {
    return __builtin_amdgcn_mfma_f32_16x16x32_bf16(a, b, c, 0, 0, 0);
}

// workspace layout (shorts)
#define XB_OFF    0                        // bf16 [32][188][24]
#define XB_ELTS   (BB*NN*24)               // 144384
#define W1S_OFF   (XB_OFF + XB_ELTS)       // A-frags [8 f][64 lanes][8]
#define W1S_ELTS  (8*64*8)                 // 4096
#define W2S_OFF   (W1S_OFF + W1S_ELTS)     // A-frags [16 f][64 lanes][8]
#define W2S_ELTS  (16*64*8)                // 8192
#define W3S_OFF   (W2S_OFF + W2S_ELTS)     // A-frags [2 s][64 lanes][8]
#define W3S_ELTS  (2*64*8)                 // 1024
#define SHORT_TOTAL (W3S_OFF + W3S_ELTS)

// MFMA-k position (q, e) -> neuron offset within a 32-block
__device__ __forceinline__ int kmap(int q, int e) {
    return (e < 4) ? (q*4 + e) : (16 + q*4 + (e - 4));
}

__global__ void prep_kernel(const float* __restrict__ x,
                            const float* __restrict__ w1,
                            const float* __restrict__ w2,
                            const float* __restrict__ w3,
                            short* __restrict__ ws,
                            int* __restrict__ cnt)
{
    const int i = blockIdx.x * blockDim.x + threadIdx.x;
    const int stride = gridDim.x * blockDim.x;
    if (i < BB) cnt[i] = 0;                                  // fc arrival ctrs
    for (int idx = i; idx < BB*NN*PP; idx += stride) {       // x -> xb
        int row = idx >> 4, k = idx & 15;
        ws[XB_OFF + row*24 + k] = f2bf(x[idx]);
    }
    for (int idx = i; idx < W1S_ELTS; idx += stride) {       // w1 -> A-frags
        int t = idx >> 9;
        int l = (idx >> 3) & 63;
        int e = idx & 7;
        int q = l >> 4, n16 = l & 15;
        ws[W1S_OFF + idx] = f2bf(w1[(q*8 + e)*HID + t*16 + n16]);
    }
    for (int idx = i; idx < W2S_ELTS; idx += stride) {       // w2 -> A-frags
        int f = idx >> 9;
        int l = (idx >> 3) & 63;
        int e = idx & 7;
        int tt = f >> 2, s = f & 3;
        int q = l >> 4, n16 = l & 15;
        int k = 32*s + kmap(q, e);
        int n = tt*16 + n16;
        ws[W2S_OFF + idx] = f2bf(w2[k*HH2 + n]);
    }
    for (int idx = i; idx < W3S_ELTS; idx += stride) {       // w3 -> A-frags
        int s2 = idx >> 9;
        int l = (idx >> 3) & 63;
        int e = idx & 7;
        int q = l >> 4, n16 = l & 15;
        int k = 32*s2 + kmap(q, e);
        ws[W3S_OFF + idx] = (n16 < DE) ? f2bf(w3[k*DE + n16]) : (short)0;
    }
}

// One edge-tile: layer1(2 MFMA + pack) x4 s-steps fused with layer2 (A2 from
// LDS), then layer3 (regs). s=0 / s2=0 peeled: bias enters as MFMA C-in.
// w2b = sW2 + lane*8 (per-lane base; frag f at +f*512 shorts, b128-linear).
#define EDGE_TILE(E1C, MASKED, TI)                                              \
    {                                                                           \
        float4_ C2[4];                                                          \
        {                                                                       \
            short8 A0 = *(const short8*)(w2b + 0*512);                          \
            short8 A1 = *(const short8*)(w2b + 4*512);                          \
            short8 A2t = *(const short8*)(w2b + 8*512);                         \
            short8 A3 = *(const short8*)(w2b + 12*512);                         \
            float4_ Ca = mfma16(W1f[0], (E1C), cbv[0]);                         \
            float4_ Cb = mfma16(W1f[1], (E1C), cbv[1]);                         \
            uint4_ dv = (uint4_){ relu_pk(Ca[0], Ca[1]), relu_pk(Ca[2], Ca[3]),  \
                                  relu_pk(Cb[0], Cb[1]), relu_pk(Cb[2], Cb[3]) };\
            short8 Bf = __builtin_bit_cast(short8, dv);                         \
            C2[0] = mfma16(A0,  Bf, bias2v[0]);                                 \
            C2[1] = mfma16(A1,  Bf, bias2v[1]);                                 \
            C2[2] = mfma16(A2t, Bf, bias2v[2]);                                 \
            C2[3] = mfma16(A3,  Bf, bias2v[3]);                                 \
        }                                                                       \
        _Pragma("unroll")                                                       \
        for (int s = 1; s < 4; ++s) {                                           \
            short8 A0 = *(const short8*)(w2b + (s)*512);                        \
            short8 A1 = *(const short8*)(w2b + (4+s)*512);                      \
            short8 A2t = *(const short8*)(w2b + (8+s)*512);                     \
            short8 A3 = *(const short8*)(w2b + (12+s)*512);                     \
            float4_ Ca = mfma16(W1f[2*s],   (E1C), cbv[2*s]);                   \
            float4_ Cb = mfma16(W1f[2*s+1], (E1C), cbv[2*s+1]);                 \
            uint4_ dv = (uint4_){ relu_pk(Ca[0], Ca[1]), relu_pk(Ca[2], Ca[3]),  \
                                  relu_pk(Cb[0], Cb[1]), relu_pk(Cb[2], Cb[3]) };\
            short8 Bf = __builtin_bit_cast(short8, dv);                         \
            C2[0] = mfma16(A0,  Bf, C2[0]);                                     \
            C2[1] = mfma16(A1,  Bf, C2[1]);                                     \
            C2[2] = mfma16(A2t, Bf, C2[2]);                                     \
            C2[3] = mfma16(A3,  Bf, C2[3]);                                     \
        }                                                                       \
        float4_ C3;                                                             \
        {                                                                       \
            uint4_ dv = (uint4_){ relu_pk(C2[0][0], C2[0][1]), relu_pk(C2[0][2], C2[0][3]), \
                                  relu_pk(C2[1][0], C2[1][1]), relu_pk(C2[1][2], C2[1][3]) }; \
            C3 = mfma16(W3f[0], __builtin_bit_cast(short8, dv), bias3r);        \
        }                                                                       \
        {                                                                       \
            uint4_ dv = (uint4_){ relu_pk(C2[2][0], C2[2][1]), relu_pk(C2[2][2], C2[2][3]), \
                                  relu_pk(C2[3][0], C2[3][1]), relu_pk(C2[3][2], C2[3][3]) }; \
            C3 = mfma16(W3f[1], __builtin_bit_cast(short8, dv), C3);            \
        }                                                                       \
        if (MASKED) {                                                           \
            const bool ok = ((TI)*16 + n16 < NN-1);                             \
            _Pragma("unroll")                                                   \
            for (int rg = 0; rg < 4; ++rg) {                                    \
                float v = C3[rg] > 0.f ? C3[rg] : 0.f;                          \
                acc[rg] += ok ? v : 0.f;                                        \
            }                                                                   \
        } else {                                                                \
            _Pragma("unroll")                                                   \
            for (int rg = 0; rg < 4; ++rg)                                      \
                acc[rg] += C3[rg] > 0.f ? C3[rg] : 0.f;                         \
        }                                                                       \
    }

// ---------------------------------------------------------------------------
// Edge MLP: 32 -> 128 relu -> 64 relu -> 5 relu, summed over 187 edges of one
// (batch, receiver). One receiver PER WAVE; 4 waves/block; W2 in 16KB LDS,
// everything else register-resident (all-arch-VGPR at waves_per_eu(3)).
// ---------------------------------------------------------------------------
__global__ __launch_bounds__(256) __attribute__((amdgpu_waves_per_eu(3)))
void edge_mfma_kernel(const short* __restrict__ ws_s,
                      const float* __restrict__ b1,
                      const float* __restrict__ b2,
                      const float* __restrict__ b3,
                      float* __restrict__ ebar)
{
    const short* xb  = ws_s + XB_OFF;
    const short* w1g = ws_s + W1S_OFF;
    const short* w3g = ws_s + W3S_OFF;

    __shared__ __align__(16) short sW2[W2S_ELTS];   // 16 KB

    const int tid  = threadIdx.x;
    const int wave = tid >> 6;
    const int lane = tid & 63;
    const int n16  = lane & 15;
    const int q    = lane >> 4;
    const int bi   = blockIdx.x * 4 + wave;   // b*188 + recv (one per wave)
    const int b    = bi / NN;
    const int recv = bi - b*NN;

    // stage W2 frags: 16384 B = 1024 uint4, exactly 4 per thread
    {
        const uint4* src = (const uint4*)(ws_s + W2S_OFF);
        uint4* dst = (uint4*)sW2;
        #pragma unroll
        for (int i = 0; i < 4; ++i) dst[tid + i*256] = src[tid + i*256];
    }

    short8 W1f[8];
    #pragma unroll
    for (int t = 0; t < 8; ++t)
        W1f[t] = *(const short8*)(w1g + t*512 + lane*8);
    short8 W3f[2];
    #pragma unroll
    for (int s = 0; s < 2; ++s)
        W3f[s] = *(const short8*)(w3g + s*512 + lane*8);
    float4_ cbv[8];
    #pragma unroll
    for (int t = 0; t < 8; ++t)
        cbv[t] = *(const float4_*)(b1 + t*16 + q*4);
    float4_ bias2v[4];
    #pragma unroll
    for (int tt = 0; tt < 4; ++tt)
        bias2v[tt] = *(const float4_*)(b2 + tt*16 + q*4);
    float4_ bias3r;
    #pragma unroll
    for (int rg = 0; rg < 4; ++rg) {
        int o = q*4 + rg;
        bias3r[rg] = (o < DE) ? b3[o] : 0.f;
    }

    __syncthreads();                         // sW2 ready

    const short* w2b = sW2 + lane*8;         // per-lane LDS base
    const short* xrow = xb + b*(NN*24);
    const bool rside = (q < 2);
    const int qoff = (q & 1)*8;

    float acc[4] = {0.f, 0.f, 0.f, 0.f};

    short8 E1;
    {
        int send0 = n16 + (n16 >= recv ? 1 : 0);
        const int node = rside ? recv : send0;
        E1 = *(const short8*)(xrow + node*24 + qoff);
    }

    #pragma unroll 1
    for (int ti = 0; ti < 11; ++ti) {
        short8 E1c = E1;
        {
            int en = (ti+1)*16 + n16;
            int send = en + (en >= recv ? 1 : 0);
            if (send > NN-1) send = NN-1;
            const int node = rside ? recv : send;
            E1 = *(const short8*)(xrow + node*24 + qoff);
        }
        EDGE_TILE(E1c, false, ti)
    }
    EDGE_TILE(E1, true, 11)

    #pragma unroll
    for (int rg = 0; rg < 4; ++rg) {
        acc[rg] += __shfl_xor(acc[rg], 1);
        acc[rg] += __shfl_xor(acc[rg], 2);
        acc[rg] += __shfl_xor(acc[rg], 4);
        acc[rg] += __shfl_xor(acc[rg], 8);
    }
    if (n16 == 0) {
        #pragma unroll
        for (int rg = 0; rg < 4; ++rg) {
            int o = q*4 + rg;
            if (o < DE) ebar[bi*DE + o] = acc[rg];
        }
    }
}

// ---------------------------------------------------------------------------
// Object MLP: [x(16)|Ebar(5)] -> 128 -> 64 -> 6 relu.
// RT=16 rows/block, 376 blocks x 256 threads (1.5 blocks/CU).
// ---------------------------------------------------------------------------
__global__ __launch_bounds__(256)
void obj_mlp_kernel(const float* __restrict__ x, const float* __restrict__ ebar,
                    const float* __restrict__ w1, const float* __restrict__ b1,
                    const float* __restrict__ w2, const float* __restrict__ b2,
                    const float* __restrict__ w3, const float* __restrict__ b3,
                    float* __restrict__ o_out)
{
    __shared__ float sW[HID*HH2];
    __shared__ float sB1[HID];
    __shared__ float sB2[HH2];
    __shared__ float sCin[RTO*KO];
    __shared__ float sH1[RTO*HID];
    __shared__ float sH2t[HH2*(RTO+1)];
    const int tid = threadIdx.x;
    const int rbase = blockIdx.x * RTO;

    for (int i = tid; i < KO*HID; i += 256) sW[i] = w1[i];
    if (tid < HID) sB1[tid] = b1[tid];
    else if (tid < HID+HH2) sB2[tid-HID] = b2[tid-HID];
    for (int i = tid; i < RTO*KO; i += 256) {
        int r = i / KO, k = i - r*KO;
        int gr = rbase + r;
        int b = gr / NN;
        int node = gr - b*NN;
        sCin[i] = (k < PP) ? x[(b*NN+node)*PP + k]
                           : ebar[(b*NN+node)*DE + (k-PP)];
    }
    __syncthreads();

    {   // layer 1: 2 groups x 8 rows
        const int j = tid & (HID-1);
        const int g = tid >> 7;
        float w[KO];
        #pragma unroll
        for (int k = 0; k < KO; ++k) w[k] = sW[k*HID + j];
        const float bj = sB1[j];
        #pragma unroll
        for (int rr = 0; rr < 8; ++rr) {
            const int r = g*8 + rr;
            const float* e = &sCin[r*KO];
            float a0=0.f,a1=0.f,a2=0.f;
            #pragma unroll
            for (int k = 0; k < KO; k += 3) {
                a0 += w[k+0]*e[k+0];
                a1 += w[k+1]*e[k+1];
                a2 += w[k+2]*e[k+2];
            }
            float v = a0+a1+a2+bj;
            sH1[r*HID + j] = v > 0.f ? v : 0.f;
        }
    }
    __syncthreads();
    for (int i = tid; i < HID*HH2; i += 256) sW[i] = w2[i];
    __syncthreads();

    {   // layer 2: 4 groups x 4 rows
        const int j = tid & (HH2-1);
        const int g = tid >> 6;
        float acc[4];
        #pragma unroll
        for (int rr = 0; rr < 4; ++rr) acc[rr] = sB2[j];
        #pragma unroll
        for (int kc = 0; kc < HID; kc += 32) {
            float w[32];
            #pragma unroll
            for (int kk = 0; kk < 32; ++kk) w[kk] = sW[(kc+kk)*HH2 + j];
            #pragma unroll
            for (int rr = 0; rr < 4; ++rr) {
                const float* h = &sH1[(g*4+rr)*HID + kc];
                float a0=0.f,a1=0.f,a2=0.f,a3=0.f;
                #pragma unroll
                for (int kk = 0; kk < 32; kk += 4) {
                    a0 += w[kk+0]*h[kk+0];
                    a1 += w[kk+1]*h[kk+1];
                    a2 += w[kk+2]*h[kk+2];
                    a3 += w[kk+3]*h[kk+3];
                }
                acc[rr] += (a0+a1)+(a2+a3);
            }
        }
        #pragma unroll
        for (int rr = 0; rr < 4; ++rr) {
            float v = acc[rr];
            sH2t[j*(RTO+1) + (g*4+rr)] = v > 0.f ? v : 0.f;
        }
    }
    __syncthreads();

    if (tid < RTO*DO) {     // layer 3
        const int r = tid & (RTO-1);
        const int c = tid >> 4;
        float a0=0.f,a1=0.f,a2=0.f,a3=0.f;
        #pragma unroll
        for (int k = 0; k < HH2; k += 4) {
            a0 += sH2t[(k+0)*(RTO+1)+r]*w3[(k+0)*DO+c];
            a1 += sH2t[(k+1)*(RTO+1)+r]*w3[(k+1)*DO+c];
            a2 += sH2t[(k+2)*(RTO+1)+r]*w3[(k+2)*DO+c];
            a3 += sH2t[(k+3)*(RTO+1)+r]*w3[(k+3)*DO+c];
        }
        float v = (a0+a1)+(a2+a3) + b3[c];
        v = v > 0.f ? v : 0.f;
        int gr = rbase + r;
        int b = gr / NN;
        int node = gr - b*NN;
        o_out[b*(NN*DO) + node*DO + c] = v;
    }
}

// ---------------------------------------------------------------------------
// Classifier (fused): layer 1 on 256 blocks (one per (b, 16-col group),
// 16-way k-split + LDS reduce); the 8th-arriving block of each batch runs
// layers 2+3 inline (per-batch arrival counter, device-scope).
// ---------------------------------------------------------------------------
__global__ __launch_bounds__(256)
void fc_fused_kernel(const float* __restrict__ o_in,
                     const float* __restrict__ w1, const float* __restrict__ b1,
                     const float* __restrict__ w2, const float* __restrict__ b2,
                     const float* __restrict__ w3, const float* __restrict__ b3,
                     float* __restrict__ h1_ws, int* __restrict__ cnt,
                     float* __restrict__ out)
{
    __shared__ __align__(16) float s_o[NN*DO];        // 1128 floats
    __shared__ float s_red[16][17];
    __shared__ float s_h1[HID];
    __shared__ float s_p[256];
    __shared__ float s_h2[HH2];
    __shared__ int s_last;
    const int tid = threadIdx.x;
    const int b   = blockIdx.x >> 3;
    const int cg  = blockIdx.x & 7;

    for (int i = tid; i < NN*DO; i += 256) s_o[i] = o_in[b*(NN*DO) + i];
    __syncthreads();

    {   // ---- layer 1: 16 cols x 16 k-slices ----
        const int col = tid & 15;
        const int sl  = tid >> 4;
        const int jg  = cg*16 + col;
        const int k0  = sl*71;
        const int k1  = (k0 + 71 < NN*DO) ? k0 + 71 : NN*DO;

        float a0=0.f, a1=0.f, a2=0.f, a3=0.f;
        int k = k0;
        for (; k + 3 < k1; k += 4) {
            a0 += s_o[k+0] * w1[(size_t)(k+0)*HID + jg];
            a1 += s_o[k+1] * w1[(size_t)(k+1)*HID + jg];
            a2 += s_o[k+2] * w1[(size_t)(k+2)*HID + jg];
            a3 += s_o[k+3] * w1[(size_t)(k+3)*HID + jg];
        }
        for (; k < k1; ++k)
            a0 += s_o[k] * w1[(size_t)k*HID + jg];
        s_red[col][sl] = (a0+a1)+(a2+a3);
    }
    __syncthreads();

    if (tid < 16) {
        float t = 0.f;
        #pragma unroll
        for (int s = 0; s < 16; ++s) t += s_red[tid][s];
        t += b1[cg*16 + tid];
        h1_ws[b*HID + cg*16 + tid] = t > 0.f ? t : 0.f;
    }

    // ---- arrival: 8th block of this batch runs fc23 ----
    __threadfence();                         // release h1 writes
    __syncthreads();
    if (tid == 0) {
        int prev = __hip_atomic_fetch_add(&cnt[b], 1, __ATOMIC_ACQ_REL,
                                          __HIP_MEMORY_SCOPE_AGENT);
        s_last = (prev == 7) ? 1 : 0;
    }
    __syncthreads();
    if (!s_last) return;
    __threadfence();                         // acquire other blocks' h1

    if (tid < HID) s_h1[tid] = h1_ws[b*HID + tid];
    __syncthreads();

    {
        const int j = tid & (HH2-1);
        const int qq = tid >> 6;
        float acc = 0.f;
        #pragma unroll
        for (int kk = 0; kk < 32; ++kk) {
            int k = qq*32 + kk;
            acc += s_h1[k] * w2[k*HH2 + j];
        }
        s_p[tid] = acc;
    }
    __syncthreads();
    if (tid < HH2) {
        float v = s_p[tid] + s_p[tid+64] + s_p[tid+128] + s_p[tid+192] + b2[tid];
        s_h2[tid] = v > 0.f ? v : 0.f;
    }
    __syncthreads();

    if (tid < NT) {
        float acc = b3[tid];
        #pragma unroll
        for (int k = 0; k < HH2; ++k)
            acc += s_h2[k] * w3[k*NT + tid];
        out[b*NT + tid] = acc;
    }
}

extern "C" void kernel_launch(void* const* d_in, const int* in_sizes, int n_in,
                              void* d_out, int out_size, void* d_ws, size_t ws_size,
                              hipStream_t stream) {
    (void)in_sizes; (void)n_in; (void)out_size; (void)ws_size;
    const float* x     = (const float*)d_in[0];
    const float* fr1_w = (const float*)d_in[1];
    const float* fr1_b = (const float*)d_in[2];
    const float* fr2_w = (const float*)d_in[3];
    const float* fr2_b = (const float*)d_in[4];
    const float* fr3_w = (const float*)d_in[5];
    const float* fr3_b = (const float*)d_in[6];
    const float* fo1_w = (const float*)d_in[7];
    const float* fo1_b = (const float*)d_in[8];
    const float* fo2_w = (const float*)d_in[9];
    const float* fo2_b = (const float*)d_in[10];
    const float* fo3_w = (const float*)d_in[11];
    const float* fo3_b = (const float*)d_in[12];
    const float* fc1_w = (const float*)d_in[13];
    const float* fc1_b = (const float*)d_in[14];
    const float* fc2_w = (const float*)d_in[15];
    const float* fc2_b = (const float*)d_in[16];
    const float* fc3_w = (const float*)d_in[17];
    const float* fc3_b = (const float*)d_in[18];

    short* ws_s = (short*)d_ws;
    size_t fbase = ((size_t)SHORT_TOTAL*2 + 15) & ~(size_t)15;
    float* ebar  = (float*)((char*)d_ws + fbase);           // [32][188][5]
    float* o_ws  = ebar + BB*NN*DE;                         // [32][188][6]
    float* h1_ws = o_ws + BB*NN*DO;                         // [32][128]
    int*   cnt   = (int*)(h1_ws + BB*HID);                  // [32]

    prep_kernel<<<128, 256, 0, stream>>>(x, fr1_w, fr2_w, fr3_w, ws_s, cnt);
    edge_mfma_kernel<<<(BB*NN)/4, 256, 0, stream>>>(ws_s, fr1_b, fr2_b, fr3_b, ebar);
    obj_mlp_kernel<<<ROWS_O/RTO, 256, 0, stream>>>(
        x, ebar, fo1_w, fo1_b, fo2_w, fo2_b, fo3_w, fo3_b, o_ws);
    fc_fused_kernel<<<BB*8, 256, 0, stream>>>(
        o_ws, fc1_w, fc1_b, fc2_w, fc2_b, fc3_w, fc3_b, h1_ws, cnt, (float*)d_out);
}

// Round 13
// 169.191 us; speedup vs baseline: 1.1608x; 1.1608x over previous
//
#include <hip/hip_runtime.h>

// GraphNet interaction network. Edge MLP via bf16 MFMA (fp32 accum).
// V22: BEST-VERIFIED CONFIG (r8, 147.6us) + fc23-into-fc1 fusion (the one
// V21 component that was verified correct; its regression was entirely the
// edge spill from waves_per_eu(3) -> VGPR 84 + 31MB scratch, now reverted).
// Edge = V13 verbatim (39.9us, replicated at 40+-1us across TEN structurally
// distinct schedules r2-r12: TLP/ILP/LDS/AGPR/serial/block-shape/addressing
// all flat or worse -> practical plateau; allocator-forcing attempts all
// spill). obj RTO=16 376 blk; fc: 256 blocks, 8th-arriving block per batch
// runs layers 2+3 inline (arrival counter zeroed by prep).
// Measurement note: ~80us of dur_us is harness 256MB workspace re-poison
// (2x40us fills at 6.6TB/s, r7 calibration) - uncontrollable floor.
#define BB   32
#define NN   188
#define PP   16
#define HID  128
#define HH2  64
#define DE   5
#define DO   6
#define NT   5
#define ROWS_O (BB*NN)
#define RTO  16
#define KO   (PP+DE)

typedef __attribute__((ext_vector_type(8))) short short8;     // 8 bf16 = 4 VGPRs
typedef __attribute__((ext_vector_type(4))) float float4_;
typedef __attribute__((ext_vector_type(4))) unsigned uint4_;

__device__ __forceinline__ short f2bf(float v) {              // RNE (prep only)
    union { float f; unsigned u; } a; a.f = v;
    unsigned r = a.u + 0x7fff + ((a.u >> 16) & 1);
    return (short)(r >> 16);
}
// relu both, then pack to 2xbf16 (RNE)
__device__ __forceinline__ unsigned relu_pk(float lo, float hi) {
    float l = lo > 0.f ? lo : 0.f;
    float h = hi > 0.f ? hi : 0.f;
    unsigned r;
    asm("v_cvt_pk_bf16_f32 %0, %1, %2" : "=v"(r) : "v"(l), "v"(h));
    return r;
}
__device__ __forceinline__ float4_ mfma16(short8 a, short8 b, float4_ c) {
    return __builtin_amdgcn_mfma_f32_16x16x32_bf16(a, b, c, 0, 0, 0);
}

// workspace layout (shorts)
#define XB_OFF    0                        // bf16 [32][188][24]
#define XB_ELTS   (BB*NN*24)               // 144384
#define W1S_OFF   (XB_OFF + XB_ELTS)       // A-frags [8 f][64 lanes][8]
#define W1S_ELTS  (8*64*8)                 // 4096
#define W2S_OFF   (W1S_OFF + W1S_ELTS)     // A-frags [16 f][64 lanes][8]
#define W2S_ELTS  (16*64*8)                // 8192
#define W3S_OFF   (W2S_OFF + W2S_ELTS)     // A-frags [2 s][64 lanes][8]
#define W3S_ELTS  (2*64*8)                 // 1024
#define SHORT_TOTAL (W3S_OFF + W3S_ELTS)

// MFMA-k position (q, e) -> neuron offset within a 32-block
__device__ __forceinline__ int kmap(int q, int e) {
    return (e < 4) ? (q*4 + e) : (16 + q*4 + (e - 4));
}

__global__ void prep_kernel(const float* __restrict__ x,
                            const float* __restrict__ w1,
                            const float* __restrict__ w2,
                            const float* __restrict__ w3,
                            short* __restrict__ ws,
                            int* __restrict__ cnt)
{
    const int i = blockIdx.x * blockDim.x + threadIdx.x;
    const int stride = gridDim.x * blockDim.x;
    if (i < BB) cnt[i] = 0;                                  // fc arrival ctrs
    for (int idx = i; idx < BB*NN*PP; idx += stride) {       // x -> xb
        int row = idx >> 4, k = idx & 15;
        ws[XB_OFF + row*24 + k] = f2bf(x[idx]);
    }
    for (int idx = i; idx < W1S_ELTS; idx += stride) {       // w1 -> A-frags
        int t = idx >> 9;
        int l = (idx >> 3) & 63;
        int e = idx & 7;
        int q = l >> 4, n16 = l & 15;
        ws[W1S_OFF + idx] = f2bf(w1[(q*8 + e)*HID + t*16 + n16]);
    }
    for (int idx = i; idx < W2S_ELTS; idx += stride) {       // w2 -> A-frags
        int f = idx >> 9;
        int l = (idx >> 3) & 63;
        int e = idx & 7;
        int tt = f >> 2, s = f & 3;
        int q = l >> 4, n16 = l & 15;
        int k = 32*s + kmap(q, e);
        int n = tt*16 + n16;
        ws[W2S_OFF + idx] = f2bf(w2[k*HH2 + n]);
    }
    for (int idx = i; idx < W3S_ELTS; idx += stride) {       // w3 -> A-frags
        int s2 = idx >> 9;
        int l = (idx >> 3) & 63;
        int e = idx & 7;
        int q = l >> 4, n16 = l & 15;
        int k = 32*s2 + kmap(q, e);
        ws[W3S_OFF + idx] = (n16 < DE) ? f2bf(w3[k*DE + n16]) : (short)0;
    }
}

// One edge-tile (V13): layer1(2 MFMA + pack) x4 s-steps fused with layer2,
// then layer3 (2 packs + 2 MFMA). s=0 / s2=0 peeled: bias enters as MFMA C-in.
#define EDGE_TILE(E1C, MASKED, TI)                                              \
    {                                                                           \
        float4_ C2[4];                                                          \
        {                                                                       \
            float4_ Ca = mfma16(W1f[0], (E1C), cbv[0]);                         \
            float4_ Cb = mfma16(W1f[1], (E1C), cbv[1]);                         \
            uint4_ dv = (uint4_){ relu_pk(Ca[0], Ca[1]), relu_pk(Ca[2], Ca[3]),  \
                                  relu_pk(Cb[0], Cb[1]), relu_pk(Cb[2], Cb[3]) };\
            short8 Bf = __builtin_bit_cast(short8, dv);                         \
            C2[0] = mfma16(W2f[0],  Bf, bias2v[0]);                             \
            C2[1] = mfma16(W2f[4],  Bf, bias2v[1]);                             \
            C2[2] = mfma16(W2f[8],  Bf, bias2v[2]);                             \
            C2[3] = mfma16(W2f[12], Bf, bias2v[3]);                             \
        }                                                                       \
        _Pragma("unroll")                                                       \
        for (int s = 1; s < 4; ++s) {                                           \
            float4_ Ca = mfma16(W1f[2*s],   (E1C), cbv[2*s]);                   \
            float4_ Cb = mfma16(W1f[2*s+1], (E1C), cbv[2*s+1]);                 \
            uint4_ dv = (uint4_){ relu_pk(Ca[0], Ca[1]), relu_pk(Ca[2], Ca[3]),  \
                                  relu_pk(Cb[0], Cb[1]), relu_pk(Cb[2], Cb[3]) };\
            short8 Bf = __builtin_bit_cast(short8, dv);                         \
            C2[0] = mfma16(W2f[s],    Bf, C2[0]);                               \
            C2[1] = mfma16(W2f[4+s],  Bf, C2[1]);                               \
            C2[2] = mfma16(W2f[8+s],  Bf, C2[2]);                               \
            C2[3] = mfma16(W2f[12+s], Bf, C2[3]);                               \
        }                                                                       \
        float4_ C3;                                                             \
        {                                                                       \
            uint4_ dv = (uint4_){ relu_pk(C2[0][0], C2[0][1]), relu_pk(C2[0][2], C2[0][3]), \
                                  relu_pk(C2[1][0], C2[1][1]), relu_pk(C2[1][2], C2[1][3]) }; \
            C3 = mfma16(W3f[0], __builtin_bit_cast(short8, dv), bias3r);        \
        }                                                                       \
        {                                                                       \
            uint4_ dv = (uint4_){ relu_pk(C2[2][0], C2[2][1]), relu_pk(C2[2][2], C2[2][3]), \
                                  relu_pk(C2[3][0], C2[3][1]), relu_pk(C2[3][2], C2[3][3]) }; \
            C3 = mfma16(W3f[1], __builtin_bit_cast(short8, dv), C3);            \
        }                                                                       \
        if (MASKED) {                                                           \
            const bool ok = ((TI)*16 + n16 < NN-1);                             \
            _Pragma("unroll")                                                   \
            for (int rg = 0; rg < 4; ++rg) {                                    \
                float v = C3[rg] > 0.f ? C3[rg] : 0.f;                          \
                acc[rg] += ok ? v : 0.f;                                        \
            }                                                                   \
        } else {                                                                \
            _Pragma("unroll")                                                   \
            for (int rg = 0; rg < 4; ++rg)                                      \
                acc[rg] += C3[rg] > 0.f ? C3[rg] : 0.f;                         \
        }                                                                       \
    }

// ---------------------------------------------------------------------------
// Edge MLP (V13 verbatim): 32 -> 128 relu -> 64 relu -> 5 relu, summed over
// 187 edges of one (batch, receiver). One receiver PER WAVE; 4 waves/block;
// ZERO LDS. 12 edge-tiles of 16 per wave, tile 11 peeled.
// ---------------------------------------------------------------------------
__global__ __launch_bounds__(256) __attribute__((amdgpu_waves_per_eu(2, 2)))
void edge_mfma_kernel(const short* __restrict__ ws_s,
                      const float* __restrict__ b1,
                      const float* __restrict__ b2,
                      const float* __restrict__ b3,
                      float* __restrict__ ebar)
{
    const short* xb  = ws_s + XB_OFF;
    const short* w1g = ws_s + W1S_OFF;
    const short* w2g = ws_s + W2S_OFF;
    const short* w3g = ws_s + W3S_OFF;

    const int tid  = threadIdx.x;
    const int wave = tid >> 6;
    const int lane = tid & 63;
    const int n16  = lane & 15;
    const int q    = lane >> 4;
    const int bi   = blockIdx.x * 4 + wave;   // b*188 + recv (one per wave)
    const int b    = bi / NN;
    const int recv = bi - b*NN;

    short8 W1f[8];
    #pragma unroll
    for (int t = 0; t < 8; ++t)
        W1f[t] = *(const short8*)(w1g + t*512 + lane*8);
    short8 W2f[16];
    #pragma unroll
    for (int f = 0; f < 16; ++f)
        W2f[f] = *(const short8*)(w2g + f*512 + lane*8);
    short8 W3f[2];
    #pragma unroll
    for (int s = 0; s < 2; ++s)
        W3f[s] = *(const short8*)(w3g + s*512 + lane*8);
    float4_ cbv[8];
    #pragma unroll
    for (int t = 0; t < 8; ++t)
        cbv[t] = *(const float4_*)(b1 + t*16 + q*4);
    float4_ bias2v[4];
    #pragma unroll
    for (int tt = 0; tt < 4; ++tt)
        bias2v[tt] = *(const float4_*)(b2 + tt*16 + q*4);
    float4_ bias3r;
    #pragma unroll
    for (int rg = 0; rg < 4; ++rg) {
        int o = q*4 + rg;
        bias3r[rg] = (o < DE) ? b3[o] : 0.f;
    }

    const short* xrow = xb + b*(NN*24);
    const bool rside = (q < 2);
    const int qoff = (q & 1)*8;

    float acc[4] = {0.f, 0.f, 0.f, 0.f};

    short8 E1;
    {
        int send0 = n16 + (n16 >= recv ? 1 : 0);
        const int node = rside ? recv : send0;
        E1 = *(const short8*)(xrow + node*24 + qoff);
    }

    #pragma unroll 1
    for (int ti = 0; ti < 11; ++ti) {
        short8 E1c = E1;
        {
            int en = (ti+1)*16 + n16;
            int send = en + (en >= recv ? 1 : 0);
            if (send > NN-1) send = NN-1;
            const int node = rside ? recv : send;
            E1 = *(const short8*)(xrow + node*24 + qoff);
        }
        EDGE_TILE(E1c, false, ti)
    }
    EDGE_TILE(E1, true, 11)

    #pragma unroll
    for (int rg = 0; rg < 4; ++rg) {
        acc[rg] += __shfl_xor(acc[rg], 1);
        acc[rg] += __shfl_xor(acc[rg], 2);
        acc[rg] += __shfl_xor(acc[rg], 4);
        acc[rg] += __shfl_xor(acc[rg], 8);
    }
    if (n16 == 0) {
        #pragma unroll
        for (int rg = 0; rg < 4; ++rg) {
            int o = q*4 + rg;
            if (o < DE) ebar[bi*DE + o] = acc[rg];
        }
    }
}

// ---------------------------------------------------------------------------
// Object MLP: [x(16)|Ebar(5)] -> 128 -> 64 -> 6 relu.
// RT=16 rows/block, 376 blocks x 256 threads (1.5 blocks/CU).
// ---------------------------------------------------------------------------
__global__ __launch_bounds__(256)
void obj_mlp_kernel(const float* __restrict__ x, const float* __restrict__ ebar,
                    const float* __restrict__ w1, const float* __restrict__ b1,
                    const float* __restrict__ w2, const float* __restrict__ b2,
                    const float* __restrict__ w3, const float* __restrict__ b3,
                    float* __restrict__ o_out)
{
    __shared__ float sW[HID*HH2];
    __shared__ float sB1[HID];
    __shared__ float sB2[HH2];
    __shared__ float sCin[RTO*KO];
    __shared__ float sH1[RTO*HID];
    __shared__ float sH2t[HH2*(RTO+1)];
    const int tid = threadIdx.x;
    const int rbase = blockIdx.x * RTO;

    for (int i = tid; i < KO*HID; i += 256) sW[i] = w1[i];
    if (tid < HID) sB1[tid] = b1[tid];
    else if (tid < HID+HH2) sB2[tid-HID] = b2[tid-HID];
    for (int i = tid; i < RTO*KO; i += 256) {
        int r = i / KO, k = i - r*KO;
        int gr = rbase + r;
        int b = gr / NN;
        int node = gr - b*NN;
        sCin[i] = (k < PP) ? x[(b*NN+node)*PP + k]
                           : ebar[(b*NN+node)*DE + (k-PP)];
    }
    __syncthreads();

    {   // layer 1: 2 groups x 8 rows
        const int j = tid & (HID-1);
        const int g = tid >> 7;
        float w[KO];
        #pragma unroll
        for (int k = 0; k < KO; ++k) w[k] = sW[k*HID + j];
        const float bj = sB1[j];
        #pragma unroll
        for (int rr = 0; rr < 8; ++rr) {
            const int r = g*8 + rr;
            const float* e = &sCin[r*KO];
            float a0=0.f,a1=0.f,a2=0.f;
            #pragma unroll
            for (int k = 0; k < KO; k += 3) {
                a0 += w[k+0]*e[k+0];
                a1 += w[k+1]*e[k+1];
                a2 += w[k+2]*e[k+2];
            }
            float v = a0+a1+a2+bj;
            sH1[r*HID + j] = v > 0.f ? v : 0.f;
        }
    }
    __syncthreads();
    for (int i = tid; i < HID*HH2; i += 256) sW[i] = w2[i];
    __syncthreads();

    {   // layer 2: 4 groups x 4 rows
        const int j = tid & (HH2-1);
        const int g = tid >> 6;
        float acc[4];
        #pragma unroll
        for (int rr = 0; rr < 4; ++rr) acc[rr] = sB2[j];
        #pragma unroll
        for (int kc = 0; kc < HID; kc += 32) {
            float w[32];
            #pragma unroll
            for (int kk = 0; kk < 32; ++kk) w[kk] = sW[(kc+kk)*HH2 + j];
            #pragma unroll
            for (int rr = 0; rr < 4; ++rr) {
                const float* h = &sH1[(g*4+rr)*HID + kc];
                float a0=0.f,a1=0.f,a2=0.f,a3=0.f;
                #pragma unroll
                for (int kk = 0; kk < 32; kk += 4) {
                    a0 += w[kk+0]*h[kk+0];
                    a1 += w[kk+1]*h[kk+1];
                    a2 += w[kk+2]*h[kk+2];
                    a3 += w[kk+3]*h[kk+3];
                }
                acc[rr] += (a0+a1)+(a2+a3);
            }
        }
        #pragma unroll
        for (int rr = 0; rr < 4; ++rr) {
            float v = acc[rr];
            sH2t[j*(RTO+1) + (g*4+rr)] = v > 0.f ? v : 0.f;
        }
    }
    __syncthreads();

    if (tid < RTO*DO) {     // layer 3
        const int r = tid & (RTO-1);
        const int c = tid >> 4;
        float a0=0.f,a1=0.f,a2=0.f,a3=0.f;
        #pragma unroll
        for (int k = 0; k < HH2; k += 4) {
            a0 += sH2t[(k+0)*(RTO+1)+r]*w3[(k+0)*DO+c];
            a1 += sH2t[(k+1)*(RTO+1)+r]*w3[(k+1)*DO+c];
            a2 += sH2t[(k+2)*(RTO+1)+r]*w3[(k+2)*DO+c];
            a3 += sH2t[(k+3)*(RTO+1)+r]*w3[(k+3)*DO+c];
        }
        float v = (a0+a1)+(a2+a3) + b3[c];
        v = v > 0.f ? v : 0.f;
        int gr = rbase + r;
        int b = gr / NN;
        int node = gr - b*NN;
        o_out[b*(NN*DO) + node*DO + c] = v;
    }
}

// ---------------------------------------------------------------------------
// Classifier (fused): layer 1 on 256 blocks (one per (b, 16-col group),
// 16-way k-split + LDS reduce); the 8th-arriving block of each batch runs
// layers 2+3 inline (per-batch arrival counter, device-scope).
// ---------------------------------------------------------------------------
__global__ __launch_bounds__(256)
void fc_fused_kernel(const float* __restrict__ o_in,
                     const float* __restrict__ w1, const float* __restrict__ b1,
                     const float* __restrict__ w2, const float* __restrict__ b2,
                     const float* __restrict__ w3, const float* __restrict__ b3,
                     float* __restrict__ h1_ws, int* __restrict__ cnt,
                     float* __restrict__ out)
{
    __shared__ __align__(16) float s_o[NN*DO];        // 1128 floats
    __shared__ float s_red[16][17];
    __shared__ float s_h1[HID];
    __shared__ float s_p[256];
    __shared__ float s_h2[HH2];
    __shared__ int s_last;
    const int tid = threadIdx.x;
    const int b   = blockIdx.x >> 3;
    const int cg  = blockIdx.x & 7;

    for (int i = tid; i < NN*DO; i += 256) s_o[i] = o_in[b*(NN*DO) + i];
    __syncthreads();

    {   // ---- layer 1: 16 cols x 16 k-slices ----
        const int col = tid & 15;
        const int sl  = tid >> 4;
        const int jg  = cg*16 + col;
        const int k0  = sl*71;
        const int k1  = (k0 + 71 < NN*DO) ? k0 + 71 : NN*DO;

        float a0=0.f, a1=0.f, a2=0.f, a3=0.f;
        int k = k0;
        for (; k + 3 < k1; k += 4) {
            a0 += s_o[k+0] * w1[(size_t)(k+0)*HID + jg];
            a1 += s_o[k+1] * w1[(size_t)(k+1)*HID + jg];
            a2 += s_o[k+2] * w1[(size_t)(k+2)*HID + jg];
            a3 += s_o[k+3] * w1[(size_t)(k+3)*HID + jg];
        }
        for (; k < k1; ++k)
            a0 += s_o[k] * w1[(size_t)k*HID + jg];
        s_red[col][sl] = (a0+a1)+(a2+a3);
    }
    __syncthreads();

    if (tid < 16) {
        float t = 0.f;
        #pragma unroll
        for (int s = 0; s < 16; ++s) t += s_red[tid][s];
        t += b1[cg*16 + tid];
        h1_ws[b*HID + cg*16 + tid] = t > 0.f ? t : 0.f;
    }

    // ---- arrival: 8th block of this batch runs fc23 ----
    __threadfence();                         // release h1 writes
    __syncthreads();
    if (tid == 0) {
        int prev = __hip_atomic_fetch_add(&cnt[b], 1, __ATOMIC_ACQ_REL,
                                          __HIP_MEMORY_SCOPE_AGENT);
        s_last = (prev == 7) ? 1 : 0;
    }
    __syncthreads();
    if (!s_last) return;
    __threadfence();                         // acquire other blocks' h1

    if (tid < HID) s_h1[tid] = h1_ws[b*HID + tid];
    __syncthreads();

    {
        const int j = tid & (HH2-1);
        const int qq = tid >> 6;
        float acc = 0.f;
        #pragma unroll
        for (int kk = 0; kk < 32; ++kk) {
            int k = qq*32 + kk;
            acc += s_h1[k] * w2[k*HH2 + j];
        }
        s_p[tid] = acc;
    }
    __syncthreads();
    if (tid < HH2) {
        float v = s_p[tid] + s_p[tid+64] + s_p[tid+128] + s_p[tid+192] + b2[tid];
        s_h2[tid] = v > 0.f ? v : 0.f;
    }
    __syncthreads();

    if (tid < NT) {
        float acc = b3[tid];
        #pragma unroll
        for (int k = 0; k < HH2; ++k)
            acc += s_h2[k] * w3[k*NT + tid];
        out[b*NT + tid] = acc;
    }
}

extern "C" void kernel_launch(void* const* d_in, const int* in_sizes, int n_in,
                              void* d_out, int out_size, void* d_ws, size_t ws_size,
                              hipStream_t stream) {
    (void)in_sizes; (void)n_in; (void)out_size; (void)ws_size;
    const float* x     = (const float*)d_in[0];
    const float* fr1_w = (const float*)d_in[1];
    const float* fr1_b = (const float*)d_in[2];
    const float* fr2_w = (const float*)d_in[3];
    const float* fr2_b = (const float*)d_in[4];
    const float* fr3_w = (const float*)d_in[5];
    const float* fr3_b = (const float*)d_in[6];
    const float* fo1_w = (const float*)d_in[7];
    const float* fo1_b = (const float*)d_in[8];
    const float* fo2_w = (const float*)d_in[9];
    const float* fo2_b = (const float*)d_in[10];
    const float* fo3_w = (const float*)d_in[11];
    const float* fo3_b = (const float*)d_in[12];
    const float* fc1_w = (const float*)d_in[13];
    const float* fc1_b = (const float*)d_in[14];
    const float* fc2_w = (const float*)d_in[15];
    const float* fc2_b = (const float*)d_in[16];
    const float* fc3_w = (const float*)d_in[17];
    const float* fc3_b = (const float*)d_in[18];

    short* ws_s = (short*)d_ws;
    size_t fbase = ((size_t)SHORT_TOTAL*2 + 15) & ~(size_t)15;
    float* ebar  = (float*)((char*)d_ws + fbase);           // [32][188][5]
    float* o_ws  = ebar + BB*NN*DE;                         // [32][188][6]
    float* h1_ws = o_ws + BB*NN*DO;                         // [32][128]
    int*   cnt   = (int*)(h1_ws + BB*HID);                  // [32]

    prep_kernel<<<128, 256, 0, stream>>>(x, fr1_w, fr2_w, fr3_w, ws_s, cnt);
    edge_mfma_kernel<<<(BB*NN)/4, 256, 0, stream>>>(ws_s, fr1_b, fr2_b, fr3_b, ebar);
    obj_mlp_kernel<<<ROWS_O/RTO, 256, 0, stream>>>(
        x, ebar, fo1_w, fo1_b, fo2_w, fo2_b, fo3_w, fo3_b, o_ws);
    fc_fused_kernel<<<BB*8, 256, 0, stream>>>(
        o_ws, fc1_w, fc1_b, fc2_w, fc2_b, fc3_w, fc3_b, h1_ws, cnt, (float*)d_out);
}

// Round 14
// 150.163 us; speedup vs baseline: 1.3079x; 1.1267x over previous
//
#include <hip/hip_runtime.h>

// GraphNet interaction network. Edge MLP via bf16 MFMA (fp32 accum).
// V23 == r8 EXACT (best verified, 147.6us). Session record:
//  - Edge kernel: 40+-1us across TEN structurally distinct schedules
//    (r2-r12: occupancy 10-47%, LDS/zero-LDS/split, 2-stream ILP, AGPR pin,
//    serial x4, 256/512-thr blocks, 376-6016 grids, incremental addressing).
//    Allocator-forcing (launch_bounds(,6), "+a" pins, waves_per_eu(3)) all
//    spill to scratch. 39.9us = practical plateau for this harness.
//  - fc23-into-fc1 arrival-counter fusion (r13): +19us -> REVERTED.
//  - Whole-net fusion w/ grid barrier (r7): 218us -> REVERTED.
//  - obj RT 32->16 @376blk + fc1 k-split @256blk (r8): -13.6us -> KEPT.
// Measurement floor: ~80us of dur_us is harness 256MB workspace re-poison
// (2x ~40us fillBuffer at ~6.7TB/s, r7 calibration + visible in profiles).
#define BB   32
#define NN   188
#define PP   16
#define HID  128
#define HH2  64
#define DE   5
#define DO   6
#define NT   5
#define ROWS_O (BB*NN)
#define RTO  16
#define KO   (PP+DE)

typedef __attribute__((ext_vector_type(8))) short short8;     // 8 bf16 = 4 VGPRs
typedef __attribute__((ext_vector_type(4))) float float4_;
typedef __attribute__((ext_vector_type(4))) unsigned uint4_;

__device__ __forceinline__ short f2bf(float v) {              // RNE (prep only)
    union { float f; unsigned u; } a; a.f = v;
    unsigned r = a.u + 0x7fff + ((a.u >> 16) & 1);
    return (short)(r >> 16);
}
// relu both, then pack to 2xbf16 (RNE)
__device__ __forceinline__ unsigned relu_pk(float lo, float hi) {
    float l = lo > 0.f ? lo : 0.f;
    float h = hi > 0.f ? hi : 0.f;
    unsigned r;
    asm("v_cvt_pk_bf16_f32 %0, %1, %2" : "=v"(r) : "v"(l), "v"(h));
    return r;
}
__device__ __forceinline__ float4_ mfma16(short8 a, short8 b, float4_ c) {
    return __builtin_amdgcn_mfma_f32_16x16x32_bf16(a, b, c, 0, 0, 0);
}

// workspace layout (shorts)
#define XB_OFF    0                        // bf16 [32][188][24]
#define XB_ELTS   (BB*NN*24)               // 144384
#define W1S_OFF   (XB_OFF + XB_ELTS)       // A-frags [8 f][64 lanes][8]
#define W1S_ELTS  (8*64*8)                 // 4096
#define W2S_OFF   (W1S_OFF + W1S_ELTS)     // A-frags [16 f][64 lanes][8]
#define W2S_ELTS  (16*64*8)                // 8192
#define W3S_OFF   (W2S_OFF + W2S_ELTS)     // A-frags [2 s][64 lanes][8]
#define W3S_ELTS  (2*64*8)                 // 1024
#define SHORT_TOTAL (W3S_OFF + W3S_ELTS)

// MFMA-k position (q, e) -> neuron offset within a 32-block
__device__ __forceinline__ int kmap(int q, int e) {
    return (e < 4) ? (q*4 + e) : (16 + q*4 + (e - 4));
}

__global__ void prep_kernel(const float* __restrict__ x,
                            const float* __restrict__ w1,
                            const float* __restrict__ w2,
                            const float* __restrict__ w3,
                            short* __restrict__ ws)
{
    const int i = blockIdx.x * blockDim.x + threadIdx.x;
    const int stride = gridDim.x * blockDim.x;
    for (int idx = i; idx < BB*NN*PP; idx += stride) {       // x -> xb
        int row = idx >> 4, k = idx & 15;
        ws[XB_OFF + row*24 + k] = f2bf(x[idx]);
    }
    for (int idx = i; idx < W1S_ELTS; idx += stride) {       // w1 -> A-frags
        int t = idx >> 9;
        int l = (idx >> 3) & 63;
        int e = idx & 7;
        int q = l >> 4, n16 = l & 15;
        ws[W1S_OFF + idx] = f2bf(w1[(q*8 + e)*HID + t*16 + n16]);
    }
    for (int idx = i; idx < W2S_ELTS; idx += stride) {       // w2 -> A-frags
        int f = idx >> 9;
        int l = (idx >> 3) & 63;
        int e = idx & 7;
        int tt = f >> 2, s = f & 3;
        int q = l >> 4, n16 = l & 15;
        int k = 32*s + kmap(q, e);
        int n = tt*16 + n16;
        ws[W2S_OFF + idx] = f2bf(w2[k*HH2 + n]);
    }
    for (int idx = i; idx < W3S_ELTS; idx += stride) {       // w3 -> A-frags
        int s2 = idx >> 9;
        int l = (idx >> 3) & 63;
        int e = idx & 7;
        int q = l >> 4, n16 = l & 15;
        int k = 32*s2 + kmap(q, e);
        ws[W3S_OFF + idx] = (n16 < DE) ? f2bf(w3[k*DE + n16]) : (short)0;
    }
}

// One edge-tile (V13): layer1(2 MFMA + pack) x4 s-steps fused with layer2,
// then layer3 (2 packs + 2 MFMA). s=0 / s2=0 peeled: bias enters as MFMA C-in.
#define EDGE_TILE(E1C, MASKED, TI)                                              \
    {                                                                           \
        float4_ C2[4];                                                          \
        {                                                                       \
            float4_ Ca = mfma16(W1f[0], (E1C), cbv[0]);                         \
            float4_ Cb = mfma16(W1f[1], (E1C), cbv[1]);                         \
            uint4_ dv = (uint4_){ relu_pk(Ca[0], Ca[1]), relu_pk(Ca[2], Ca[3]),  \
                                  relu_pk(Cb[0], Cb[1]), relu_pk(Cb[2], Cb[3]) };\
            short8 Bf = __builtin_bit_cast(short8, dv);                         \
            C2[0] = mfma16(W2f[0],  Bf, bias2v[0]);                             \
            C2[1] = mfma16(W2f[4],  Bf, bias2v[1]);                             \
            C2[2] = mfma16(W2f[8],  Bf, bias2v[2]);                             \
            C2[3] = mfma16(W2f[12], Bf, bias2v[3]);                             \
        }                                                                       \
        _Pragma("unroll")                                                       \
        for (int s = 1; s < 4; ++s) {                                           \
            float4_ Ca = mfma16(W1f[2*s],   (E1C), cbv[2*s]);                   \
            float4_ Cb = mfma16(W1f[2*s+1], (E1C), cbv[2*s+1]);                 \
            uint4_ dv = (uint4_){ relu_pk(Ca[0], Ca[1]), relu_pk(Ca[2], Ca[3]),  \
                                  relu_pk(Cb[0], Cb[1]), relu_pk(Cb[2], Cb[3]) };\
            short8 Bf = __builtin_bit_cast(short8, dv);                         \
            C2[0] = mfma16(W2f[s],    Bf, C2[0]);                               \
            C2[1] = mfma16(W2f[4+s],  Bf, C2[1]);                               \
            C2[2] = mfma16(W2f[8+s],  Bf, C2[2]);                               \
            C2[3] = mfma16(W2f[12+s], Bf, C2[3]);                               \
        }                                                                       \
        float4_ C3;                                                             \
        {                                                                       \
            uint4_ dv = (uint4_){ relu_pk(C2[0][0], C2[0][1]), relu_pk(C2[0][2], C2[0][3]), \
                                  relu_pk(C2[1][0], C2[1][1]), relu_pk(C2[1][2], C2[1][3]) }; \
            C3 = mfma16(W3f[0], __builtin_bit_cast(short8, dv), bias3r);        \
        }                                                                       \
        {                                                                       \
            uint4_ dv = (uint4_){ relu_pk(C2[2][0], C2[2][1]), relu_pk(C2[2][2], C2[2][3]), \
                                  relu_pk(C2[3][0], C2[3][1]), relu_pk(C2[3][2], C2[3][3]) }; \
            C3 = mfma16(W3f[1], __builtin_bit_cast(short8, dv), C3);            \
        }                                                                       \
        if (MASKED) {                                                           \
            const bool ok = ((TI)*16 + n16 < NN-1);                             \
            _Pragma("unroll")                                                   \
            for (int rg = 0; rg < 4; ++rg) {                                    \
                float v = C3[rg] > 0.f ? C3[rg] : 0.f;                          \
                acc[rg] += ok ? v : 0.f;                                        \
            }                                                                   \
        } else {                                                                \
            _Pragma("unroll")                                                   \
            for (int rg = 0; rg < 4; ++rg)                                      \
                acc[rg] += C3[rg] > 0.f ? C3[rg] : 0.f;                         \
        }                                                                       \
    }

// ---------------------------------------------------------------------------
// Edge MLP (V13 verbatim): 32 -> 128 relu -> 64 relu -> 5 relu, summed over
// 187 edges of one (batch, receiver). One receiver PER WAVE; 4 waves/block;
// ZERO LDS. 12 edge-tiles of 16 per wave, tile 11 peeled.
// ---------------------------------------------------------------------------
__global__ __launch_bounds__(256) __attribute__((amdgpu_waves_per_eu(2, 2)))
void edge_mfma_kernel(const short* __restrict__ ws_s,
                      const float* __restrict__ b1,
                      const float* __restrict__ b2,
                      const float* __restrict__ b3,
                      float* __restrict__ ebar)
{
    const short* xb  = ws_s + XB_OFF;
    const short* w1g = ws_s + W1S_OFF;
    const short* w2g = ws_s + W2S_OFF;
    const short* w3g = ws_s + W3S_OFF;

    const int tid  = threadIdx.x;
    const int wave = tid >> 6;
    const int lane = tid & 63;
    const int n16  = lane & 15;
    const int q    = lane >> 4;
    const int bi   = blockIdx.x * 4 + wave;   // b*188 + recv (one per wave)
    const int b    = bi / NN;
    const int recv = bi - b*NN;

    short8 W1f[8];
    #pragma unroll
    for (int t = 0; t < 8; ++t)
        W1f[t] = *(const short8*)(w1g + t*512 + lane*8);
    short8 W2f[16];
    #pragma unroll
    for (int f = 0; f < 16; ++f)
        W2f[f] = *(const short8*)(w2g + f*512 + lane*8);
    short8 W3f[2];
    #pragma unroll
    for (int s = 0; s < 2; ++s)
        W3f[s] = *(const short8*)(w3g + s*512 + lane*8);
    float4_ cbv[8];
    #pragma unroll
    for (int t = 0; t < 8; ++t)
        cbv[t] = *(const float4_*)(b1 + t*16 + q*4);
    float4_ bias2v[4];
    #pragma unroll
    for (int tt = 0; tt < 4; ++tt)
        bias2v[tt] = *(const float4_*)(b2 + tt*16 + q*4);
    float4_ bias3r;
    #pragma unroll
    for (int rg = 0; rg < 4; ++rg) {
        int o = q*4 + rg;
        bias3r[rg] = (o < DE) ? b3[o] : 0.f;
    }

    const short* xrow = xb + b*(NN*24);
    const bool rside = (q < 2);
    const int qoff = (q & 1)*8;

    float acc[4] = {0.f, 0.f, 0.f, 0.f};

    short8 E1;
    {
        int send0 = n16 + (n16 >= recv ? 1 : 0);
        const int node = rside ? recv : send0;
        E1 = *(const short8*)(xrow + node*24 + qoff);
    }

    #pragma unroll 1
    for (int ti = 0; ti < 11; ++ti) {
        short8 E1c = E1;
        {
            int en = (ti+1)*16 + n16;
            int send = en + (en >= recv ? 1 : 0);
            if (send > NN-1) send = NN-1;
            const int node = rside ? recv : send;
            E1 = *(const short8*)(xrow + node*24 + qoff);
        }
        EDGE_TILE(E1c, false, ti)
    }
    EDGE_TILE(E1, true, 11)

    #pragma unroll
    for (int rg = 0; rg < 4; ++rg) {
        acc[rg] += __shfl_xor(acc[rg], 1);
        acc[rg] += __shfl_xor(acc[rg], 2);
        acc[rg] += __shfl_xor(acc[rg], 4);
        acc[rg] += __shfl_xor(acc[rg], 8);
    }
    if (n16 == 0) {
        #pragma unroll
        for (int rg = 0; rg < 4; ++rg) {
            int o = q*4 + rg;
            if (o < DE) ebar[bi*DE + o] = acc[rg];
        }
    }
}

// ---------------------------------------------------------------------------
// Object MLP: [x(16)|Ebar(5)] -> 128 -> 64 -> 6 relu.
// RT=16 rows/block, 376 blocks x 256 threads (1.5 blocks/CU).
// ---------------------------------------------------------------------------
__global__ __launch_bounds__(256)
void obj_mlp_kernel(const float* __restrict__ x, const float* __restrict__ ebar,
                    const float* __restrict__ w1, const float* __restrict__ b1,
                    const float* __restrict__ w2, const float* __restrict__ b2,
                    const float* __restrict__ w3, const float* __restrict__ b3,
                    float* __restrict__ o_out)
{
    __shared__ float sW[HID*HH2];
    __shared__ float sB1[HID];
    __shared__ float sB2[HH2];
    __shared__ float sCin[RTO*KO];
    __shared__ float sH1[RTO*HID];
    __shared__ float sH2t[HH2*(RTO+1)];
    const int tid = threadIdx.x;
    const int rbase = blockIdx.x * RTO;

    for (int i = tid; i < KO*HID; i += 256) sW[i] = w1[i];
    if (tid < HID) sB1[tid] = b1[tid];
    else if (tid < HID+HH2) sB2[tid-HID] = b2[tid-HID];
    for (int i = tid; i < RTO*KO; i += 256) {
        int r = i / KO, k = i - r*KO;
        int gr = rbase + r;
        int b = gr / NN;
        int node = gr - b*NN;
        sCin[i] = (k < PP) ? x[(b*NN+node)*PP + k]
                           : ebar[(b*NN+node)*DE + (k-PP)];
    }
    __syncthreads();

    {   // layer 1: 2 groups x 8 rows
        const int j = tid & (HID-1);
        const int g = tid >> 7;
        float w[KO];
        #pragma unroll
        for (int k = 0; k < KO; ++k) w[k] = sW[k*HID + j];
        const float bj = sB1[j];
        #pragma unroll
        for (int rr = 0; rr < 8; ++rr) {
            const int r = g*8 + rr;
            const float* e = &sCin[r*KO];
            float a0=0.f,a1=0.f,a2=0.f;
            #pragma unroll
            for (int k = 0; k < KO; k += 3) {
                a0 += w[k+0]*e[k+0];
                a1 += w[k+1]*e[k+1];
                a2 += w[k+2]*e[k+2];
            }
            float v = a0+a1+a2+bj;
            sH1[r*HID + j] = v > 0.f ? v : 0.f;
        }
    }
    __syncthreads();
    for (int i = tid; i < HID*HH2; i += 256) sW[i] = w2[i];
    __syncthreads();

    {   // layer 2: 4 groups x 4 rows
        const int j = tid & (HH2-1);
        const int g = tid >> 6;
        float acc[4];
        #pragma unroll
        for (int rr = 0; rr < 4; ++rr) acc[rr] = sB2[j];
        #pragma unroll
        for (int kc = 0; kc < HID; kc += 32) {
            float w[32];
            #pragma unroll
            for (int kk = 0; kk < 32; ++kk) w[kk] = sW[(kc+kk)*HH2 + j];
            #pragma unroll
            for (int rr = 0; rr < 4; ++rr) {
                const float* h = &sH1[(g*4+rr)*HID + kc];
                float a0=0.f,a1=0.f,a2=0.f,a3=0.f;
                #pragma unroll
                for (int kk = 0; kk < 32; kk += 4) {
                    a0 += w[kk+0]*h[kk+0];
                    a1 += w[kk+1]*h[kk+1];
                    a2 += w[kk+2]*h[kk+2];
                    a3 += w[kk+3]*h[kk+3];
                }
                acc[rr] += (a0+a1)+(a2+a3);
            }
        }
        #pragma unroll
        for (int rr = 0; rr < 4; ++rr) {
            float v = acc[rr];
            sH2t[j*(RTO+1) + (g*4+rr)] = v > 0.f ? v : 0.f;
        }
    }
    __syncthreads();

    if (tid < RTO*DO) {     // layer 3
        const int r = tid & (RTO-1);
        const int c = tid >> 4;
        float a0=0.f,a1=0.f,a2=0.f,a3=0.f;
        #pragma unroll
        for (int k = 0; k < HH2; k += 4) {
            a0 += sH2t[(k+0)*(RTO+1)+r]*w3[(k+0)*DO+c];
            a1 += sH2t[(k+1)*(RTO+1)+r]*w3[(k+1)*DO+c];
            a2 += sH2t[(k+2)*(RTO+1)+r]*w3[(k+2)*DO+c];
            a3 += sH2t[(k+3)*(RTO+1)+r]*w3[(k+3)*DO+c];
        }
        float v = (a0+a1)+(a2+a3) + b3[c];
        v = v > 0.f ? v : 0.f;
        int gr = rbase + r;
        int b = gr / NN;
        int node = gr - b*NN;
        o_out[b*(NN*DO) + node*DO + c] = v;
    }
}

// ---------------------------------------------------------------------------
// Classifier layer 1: [32 b][1128] @ [1128][128] -> relu h1 [32][128].
// 256 blocks: one per (b, 16-col group). 16-way k-split + LDS reduce.
// ---------------------------------------------------------------------------
__global__ __launch_bounds__(256)
void fc1_kernel(const float* __restrict__ o_in,
                const float* __restrict__ w1, const float* __restrict__ b1,
                float* __restrict__ h1_ws)
{
    __shared__ __align__(16) float s_o[NN*DO];        // 1128 floats
    __shared__ float s_red[16][17];
    const int tid = threadIdx.x;
    const int b   = blockIdx.x >> 3;
    const int cg  = blockIdx.x & 7;

    for (int i = tid; i < NN*DO; i += 256) s_o[i] = o_in[b*(NN*DO) + i];
    __syncthreads();

    const int col = tid & 15;            // 0..15 within group
    const int sl  = tid >> 4;            // 0..15 k-slice
    const int jg  = cg*16 + col;         // global output column
    const int k0  = sl*71;
    const int k1  = (k0 + 71 < NN*DO) ? k0 + 71 : NN*DO;

    float a0=0.f, a1=0.f, a2=0.f, a3=0.f;
    int k = k0;
    for (; k + 3 < k1; k += 4) {
        a0 += s_o[k+0] * w1[(size_t)(k+0)*HID + jg];
        a1 += s_o[k+1] * w1[(size_t)(k+1)*HID + jg];
        a2 += s_o[k+2] * w1[(size_t)(k+2)*HID + jg];
        a3 += s_o[k+3] * w1[(size_t)(k+3)*HID + jg];
    }
    for (; k < k1; ++k)
        a0 += s_o[k] * w1[(size_t)k*HID + jg];
    s_red[col][sl] = (a0+a1)+(a2+a3);
    __syncthreads();

    if (tid < 16) {
        float t = 0.f;
        #pragma unroll
        for (int s = 0; s < 16; ++s) t += s_red[tid][s];
        t += b1[cg*16 + tid];
        h1_ws[b*HID + cg*16 + tid] = t > 0.f ? t : 0.f;
    }
}

// ---------------------------------------------------------------------------
// Classifier layers 2+3: h1[128] -> 64 relu -> 5. 32 blocks (one per b).
// ---------------------------------------------------------------------------
__global__ __launch_bounds__(256)
void fc23_kernel(const float* __restrict__ h1_ws,
                 const float* __restrict__ w2, const float* __restrict__ b2,
                 const float* __restrict__ w3, const float* __restrict__ b3,
                 float* __restrict__ out)
{
    __shared__ float s_h1[HID];
    __shared__ float s_p[256];
    __shared__ float s_h2[HH2];
    const int b = blockIdx.x, tid = threadIdx.x;

    if (tid < HID) s_h1[tid] = h1_ws[b*HID + tid];
    __syncthreads();

    {
        const int j = tid & (HH2-1);
        const int q = tid >> 6;
        float acc = 0.f;
        #pragma unroll
        for (int kk = 0; kk < 32; ++kk) {
            int k = q*32 + kk;
            acc += s_h1[k] * w2[k*HH2 + j];
        }
        s_p[tid] = acc;
    }
    __syncthreads();
    if (tid < HH2) {
        float v = s_p[tid] + s_p[tid+64] + s_p[tid+128] + s_p[tid+192] + b2[tid];
        s_h2[tid] = v > 0.f ? v : 0.f;
    }
    __syncthreads();

    if (tid < NT) {
        float acc = b3[tid];
        #pragma unroll
        for (int k = 0; k < HH2; ++k)
            acc += s_h2[k] * w3[k*NT + tid];
        out[b*NT + tid] = acc;
    }
}

extern "C" void kernel_launch(void* const* d_in, const int* in_sizes, int n_in,
                              void* d_out, int out_size, void* d_ws, size_t ws_size,
                              hipStream_t stream) {
    (void)in_sizes; (void)n_in; (void)out_size; (void)ws_size;
    const float* x     = (const float*)d_in[0];
    const float* fr1_w = (const float*)d_in[1];
    const float* fr1_b = (const float*)d_in[2];
    const float* fr2_w = (const float*)d_in[3];
    const float* fr2_b = (const float*)d_in[4];
    const float* fr3_w = (const float*)d_in[5];
    const float* fr3_b = (const float*)d_in[6];
    const float* fo1_w = (const float*)d_in[7];
    const float* fo1_b = (const float*)d_in[8];
    const float* fo2_w = (const float*)d_in[9];
    const float* fo2_b = (const float*)d_in[10];
    const float* fo3_w = (const float*)d_in[11];
    const float* fo3_b = (const float*)d_in[12];
    const float* fc1_w = (const float*)d_in[13];
    const float* fc1_b = (const float*)d_in[14];
    const float* fc2_w = (const float*)d_in[15];
    const float* fc2_b = (const float*)d_in[16];
    const float* fc3_w = (const float*)d_in[17];
    const float* fc3_b = (const float*)d_in[18];

    short* ws_s = (short*)d_ws;
    size_t fbase = ((size_t)SHORT_TOTAL*2 + 15) & ~(size_t)15;
    float* ebar  = (float*)((char*)d_ws + fbase);           // [32][188][5]
    float* o_ws  = ebar + BB*NN*DE;                         // [32][188][6]
    float* h1_ws = o_ws + BB*NN*DO;                         // [32][128]

    prep_kernel<<<128, 256, 0, stream>>>(x, fr1_w, fr2_w, fr3_w, ws_s);
    edge_mfma_kernel<<<(BB*NN)/4, 256, 0, stream>>>(ws_s, fr1_b, fr2_b, fr3_b, ebar);
    obj_mlp_kernel<<<ROWS_O/RTO, 256, 0, stream>>>(
        x, ebar, fo1_w, fo1_b, fo2_w, fo2_b, fo3_w, fo3_b, o_ws);
    fc1_kernel<<<BB*8, 256, 0, stream>>>(o_ws, fc1_w, fc1_b, h1_ws);
    fc23_kernel<<<BB, 256, 0, stream>>>(
        h1_ws, fc2_w, fc2_b, fc3_w, fc3_b, (float*)d_out);
}